// Round 13
// baseline (252.804 us; speedup 1.0000x reference)
//
#include <hip/hip_runtime.h>

#define N_NODES   100352
#define N_EDGES   1605632
#define IN_C      128
#define HID_C     64
#define OUT_C     32
#define NUM_GRAPHS 512
#define NPG       196
#define TOPK      30

#define NB        196     // buckets = dst>>9 (512 nodes each; 196*512 = 100352)
#define BCAP      10240   // arena capacity per bucket (E[nb]=8192, sigma~90)
#define LCAP      10240   // LDS staging capacity in k_build (40 KB)
#define NBUCKET_BLOCKS 784  // N_EDGES / (256*8)

typedef float v16f __attribute__((ext_vector_type(16)));

// ws layout (bytes)
#define OFF_DEG     0u          // int[N]
#define OFF_ROWPTR  401408u     // int[N]
#define OFF_DIS     802816u     // float[N]
#define OFF_BCNT    1204224u    // int[NB]
#define OFF_ARENA   1206272u    // int[NB*BCAP] = 8,028,160 B (packed; dead after k_build)
#define OFF_OUT2    1206272u    // float[N*32] = 12,845,056 B -- aliases arena region (16 MB reserved)
#define OFF_CSR     17262592u   // int[E]
#define OFF_XW1     23685120u   // float[N*64]  (UNSCALED x@W1)
#define OFF_H       49375232u   // float[N*64]
#define OFF_XW2     75065344u   // float[N*32]  (dis-scaled)

// FUSED phase 1: blocks [0, 784) bucketize edges (memory/atomic-bound);
// blocks [784, ...) compute raw xw1 = x @ W1 (VALU/SMEM-bound). Independent
// work, complementary pipes -> overlap hides mm1 behind the bucket pass.
__global__ __launch_bounds__(256) void k_phase1(const int* __restrict__ src, const int* __restrict__ dst,
                                                int* __restrict__ bucket_cnt, int* __restrict__ arena,
                                                const float* __restrict__ x, const float* __restrict__ W1,
                                                float* __restrict__ xw1) {
    int tid = threadIdx.x;
    if (blockIdx.x < NBUCKET_BLOCKS) {
        // ---- bucketize: packed (src<<9 | dst&511), src < 2^17 ----
        __shared__ int hist[NB];
        __shared__ int cur[NB];
        for (int i = tid; i < NB; i += 256) hist[i] = 0;
        __syncthreads();
        int e0 = (blockIdx.x * 256 + tid) * 8;       // 8 edges per thread
        int4 sa = ((const int4*)src)[e0 / 4], sb = ((const int4*)src)[e0 / 4 + 1];
        int4 da = ((const int4*)dst)[e0 / 4], db = ((const int4*)dst)[e0 / 4 + 1];
        int es[8] = {sa.x, sa.y, sa.z, sa.w, sb.x, sb.y, sb.z, sb.w};
        int ed[8] = {da.x, da.y, da.z, da.w, db.x, db.y, db.z, db.w};
        int eb[8];
#pragma unroll
        for (int j = 0; j < 8; ++j) { eb[j] = ed[j] >> 9; atomicAdd(&hist[eb[j]], 1); }
        __syncthreads();
        for (int i = tid; i < NB; i += 256) {
            int c = hist[i];
            cur[i] = (c > 0) ? atomicAdd(&bucket_cnt[i], c) : 0;
        }
        __syncthreads();
#pragma unroll
        for (int j = 0; j < 8; ++j) {
            int p = atomicAdd(&cur[eb[j]], 1);
            if (p < BCAP) arena[(size_t)eb[j] * BCAP + p] = (es[j] << 9) | (ed[j] & 511);
        }
    } else {
        // ---- raw mm1 (no dis scale): one node/thread, col-split 4-way ----
        int bid = blockIdx.x - NBUCKET_BLOCKS;
        int n = bid * 64 + (tid & 63);
        int ch = __builtin_amdgcn_readfirstlane((tid >> 6) * 16);   // col quarter -> SGPR
        const float4* xrow = (const float4*)(x + (size_t)n * IN_C);
        float acc[16];
#pragma unroll
        for (int c = 0; c < 16; ++c) acc[c] = 0.f;
        float4 xq = xrow[0];
#pragma unroll 1
        for (int q = 0; q < IN_C / 4; ++q) {
            float4 xn = xrow[(q + 1) & (IN_C / 4 - 1)];   // prefetch next chunk
            const float* wp = W1 + q * 4 * HID_C + ch;    // scalar address chain
            v16f w0, w1, w2, w3;
            asm volatile("s_load_dwordx16 %0, %1, 0x0"   : "=s"(w0) : "s"(wp));
            asm volatile("s_load_dwordx16 %0, %1, 0x100" : "=s"(w1) : "s"(wp));
            asm volatile("s_load_dwordx16 %0, %1, 0x200" : "=s"(w2) : "s"(wp));
            asm volatile("s_load_dwordx16 %0, %1, 0x300" : "=s"(w3) : "s"(wp));
            asm volatile("s_waitcnt lgkmcnt(0)" : "+s"(w0), "+s"(w1), "+s"(w2), "+s"(w3));
#pragma unroll
            for (int c = 0; c < 16; ++c) {
                acc[c] = fmaf(xq.x, w0[c], acc[c]);
                acc[c] = fmaf(xq.y, w1[c], acc[c]);
                acc[c] = fmaf(xq.z, w2[c], acc[c]);
                acc[c] = fmaf(xq.w, w3[c], acc[c]);
            }
            xq = xn;
        }
        float4* orow = (float4*)(xw1 + (size_t)n * HID_C + ch);
#pragma unroll
        for (int c4 = 0; c4 < 4; ++c4) {
            float4 o;
            o.x = acc[4 * c4 + 0];
            o.y = acc[4 * c4 + 1];
            o.z = acc[4 * c4 + 2];
            o.w = acc[4 * c4 + 3];
            orow[c4] = o;
        }
    }
}

// Pass 2: per bucket (512 nodes). Preamble scans all 196 bucket counts in-block;
// then deg/row_ptr/dis via LDS, CSR via LDS staging.
__global__ __launch_bounds__(256) void k_build(const int* __restrict__ arena, const int* __restrict__ bucket_cnt,
                                               int* __restrict__ row_ptr,
                                               int* __restrict__ deg, float* __restrict__ dis,
                                               int* __restrict__ csr_src) {
    __shared__ int bsc[256];
    __shared__ int dloc[512];
    __shared__ int sc[512];
    __shared__ int cur[512];
    __shared__ int stage[LCAP];
    int b = blockIdx.x;
    int tid = threadIdx.x;
    int bv = (tid < NB) ? bucket_cnt[tid] : 0;
    bsc[tid] = bv;
    __syncthreads();
    for (int o = 1; o < 256; o <<= 1) {
        int a = (tid >= o) ? bsc[tid - o] : 0;
        __syncthreads();
        bsc[tid] += a;
        __syncthreads();
    }
    int nb = min(bucket_cnt[b], BCAP);
    int gbase = bsc[b] - bucket_cnt[b];            // exclusive prefix for bucket b
    const int* ap = arena + (size_t)b * BCAP;
    for (int i = tid; i < 512; i += 256) dloc[i] = 0;
    __syncthreads();
    for (int i = tid; i < nb; i += 256) {
        int e = ap[i];
        atomicAdd(&dloc[e & 511], 1);
    }
    __syncthreads();
    for (int i = tid; i < 512; i += 256) sc[i] = dloc[i];
    __syncthreads();
    for (int o = 1; o < 512; o <<= 1) {        // Hillis-Steele inclusive scan, 512 elems
        int i0 = tid, i1 = tid + 256;
        int v0 = (i0 >= o) ? sc[i0 - o] : 0;
        int v1 = (i1 >= o) ? sc[i1 - o] : 0;
        __syncthreads();
        sc[i0] += v0;
        sc[i1] += v1;
        __syncthreads();
    }
    for (int i = tid; i < 512; i += 256) {
        int d = dloc[i];
        int off = sc[i] - d;                   // exclusive prefix
        int node = b * 512 + i;
        row_ptr[node] = gbase + off;
        deg[node] = d;
        dis[node] = (float)(1.0 / sqrt((double)(d + 1)));   // +1 self-loop
        cur[i] = off;
    }
    __syncthreads();
    bool inlds = (nb <= LCAP);
    for (int i = tid; i < nb; i += 256) {
        int e = ap[i];
        int p = atomicAdd(&cur[e & 511], 1);
        int sv = ((unsigned)e) >> 9;
        if (inlds) stage[p] = sv;
        else       csr_src[gbase + p] = sv;
    }
    __syncthreads();
    if (inlds)
        for (int i = tid; i < nb; i += 256) csr_src[gbase + i] = stage[i];
}

// layer-1 aggregation: one 64-lane wave per node. xw1 is UNSCALED, so the
// per-source dis[s] rides the same shuffle as the index (dj). 16 gathers in flight.
__global__ __launch_bounds__(256) void k_agg1(const float* __restrict__ xw1, const int* __restrict__ csr_src,
                                              const int* __restrict__ row_ptr, const int* __restrict__ deg,
                                              const float* __restrict__ dis, const float* __restrict__ b1,
                                              float* __restrict__ h) {
    int lane = threadIdx.x & 63;
    int v = blockIdx.x * 4 + (threadIdx.x >> 6);
    int start = row_ptr[v];
    int cnt = deg[v];
    float dv = dis[v];
    float acc0 = dv * xw1[(size_t)v * HID_C + lane];   // self-loop: dis[v]*xw1[v]
    float acc1 = 0.f, acc2 = 0.f, acc3 = 0.f;
    for (int base = 0; base < cnt; base += 64) {
        int mcnt = min(64, cnt - base);
        int sj = 0; float dj = 0.f;
        if (lane < mcnt) { sj = csr_src[start + base + lane]; dj = dis[sj]; }
        int j = 0;
        for (; j + 16 <= mcnt; j += 16) {
            int   s0 = __shfl(sj, j + 0),  s1 = __shfl(sj, j + 1),  s2 = __shfl(sj, j + 2),  s3 = __shfl(sj, j + 3);
            int   s4 = __shfl(sj, j + 4),  s5 = __shfl(sj, j + 5),  s6 = __shfl(sj, j + 6),  s7 = __shfl(sj, j + 7);
            int   s8 = __shfl(sj, j + 8),  s9 = __shfl(sj, j + 9),  sA = __shfl(sj, j + 10), sB = __shfl(sj, j + 11);
            int   sC = __shfl(sj, j + 12), sD = __shfl(sj, j + 13), sE = __shfl(sj, j + 14), sF = __shfl(sj, j + 15);
            float d0 = __shfl(dj, j + 0),  d1 = __shfl(dj, j + 1),  d2 = __shfl(dj, j + 2),  d3 = __shfl(dj, j + 3);
            float d4 = __shfl(dj, j + 4),  d5 = __shfl(dj, j + 5),  d6 = __shfl(dj, j + 6),  d7 = __shfl(dj, j + 7);
            float d8 = __shfl(dj, j + 8),  d9 = __shfl(dj, j + 9),  dA = __shfl(dj, j + 10), dB = __shfl(dj, j + 11);
            float dC = __shfl(dj, j + 12), dD = __shfl(dj, j + 13), dE = __shfl(dj, j + 14), dF = __shfl(dj, j + 15);
            float v0 = xw1[(size_t)s0 * HID_C + lane], v1 = xw1[(size_t)s1 * HID_C + lane];
            float v2 = xw1[(size_t)s2 * HID_C + lane], v3 = xw1[(size_t)s3 * HID_C + lane];
            float v4 = xw1[(size_t)s4 * HID_C + lane], v5 = xw1[(size_t)s5 * HID_C + lane];
            float v6 = xw1[(size_t)s6 * HID_C + lane], v7 = xw1[(size_t)s7 * HID_C + lane];
            float v8 = xw1[(size_t)s8 * HID_C + lane], v9 = xw1[(size_t)s9 * HID_C + lane];
            float vA = xw1[(size_t)sA * HID_C + lane], vB = xw1[(size_t)sB * HID_C + lane];
            float vC = xw1[(size_t)sC * HID_C + lane], vD = xw1[(size_t)sD * HID_C + lane];
            float vE = xw1[(size_t)sE * HID_C + lane], vF = xw1[(size_t)sF * HID_C + lane];
            acc0 = fmaf(d0, v0, acc0); acc1 = fmaf(d1, v1, acc1);
            acc2 = fmaf(d2, v2, acc2); acc3 = fmaf(d3, v3, acc3);
            acc0 = fmaf(d4, v4, acc0); acc1 = fmaf(d5, v5, acc1);
            acc2 = fmaf(d6, v6, acc2); acc3 = fmaf(d7, v7, acc3);
            acc0 = fmaf(d8, v8, acc0); acc1 = fmaf(d9, v9, acc1);
            acc2 = fmaf(dA, vA, acc2); acc3 = fmaf(dB, vB, acc3);
            acc0 = fmaf(dC, vC, acc0); acc1 = fmaf(dD, vD, acc1);
            acc2 = fmaf(dE, vE, acc2); acc3 = fmaf(dF, vF, acc3);
        }
        for (; j < mcnt; ++j) {
            int s = __shfl(sj, j);
            float d = __shfl(dj, j);
            acc0 = fmaf(d, xw1[(size_t)s * HID_C + lane], acc0);
        }
    }
    float o = fmaf(dv, (acc0 + acc1) + (acc2 + acc3), b1[lane]);
    h[(size_t)v * HID_C + lane] = fmaxf(o, 0.f);   // ReLU fused
}

// xw2s = dis[n] * (h @ W2). One node per thread, col-split 2-way (16 cols each).
__global__ __launch_bounds__(256) void k_mm2(const float* __restrict__ h, const float* __restrict__ W2,
                                             const float* __restrict__ dis, float* __restrict__ xw2s) {
    int tid = threadIdx.x;
    int n = blockIdx.x * 128 + (tid & 127);
    int ch = __builtin_amdgcn_readfirstlane((tid >> 7) * 16);   // wave-uniform col half -> SGPR
    const float4* hrow = (const float4*)(h + (size_t)n * HID_C);
    float acc[16];
#pragma unroll
    for (int c = 0; c < 16; ++c) acc[c] = 0.f;
    float4 xq = hrow[0];
#pragma unroll 1
    for (int q = 0; q < HID_C / 4; ++q) {
        float4 xn = hrow[(q + 1) & (HID_C / 4 - 1)];
        const float* wp = W2 + q * 4 * OUT_C + ch;
        v16f w0, w1, w2, w3;
        asm volatile("s_load_dwordx16 %0, %1, 0x0"   : "=s"(w0) : "s"(wp));
        asm volatile("s_load_dwordx16 %0, %1, 0x80"  : "=s"(w1) : "s"(wp));
        asm volatile("s_load_dwordx16 %0, %1, 0x100" : "=s"(w2) : "s"(wp));
        asm volatile("s_load_dwordx16 %0, %1, 0x180" : "=s"(w3) : "s"(wp));
        asm volatile("s_waitcnt lgkmcnt(0)" : "+s"(w0), "+s"(w1), "+s"(w2), "+s"(w3));
#pragma unroll
        for (int c = 0; c < 16; ++c) {
            acc[c] = fmaf(xq.x, w0[c], acc[c]);
            acc[c] = fmaf(xq.y, w1[c], acc[c]);
            acc[c] = fmaf(xq.z, w2[c], acc[c]);
            acc[c] = fmaf(xq.w, w3[c], acc[c]);
        }
        xq = xn;
    }
    float dv = dis[n];
    float4* orow = (float4*)(xw2s + (size_t)n * OUT_C + ch);
#pragma unroll
    for (int c4 = 0; c4 < 4; ++c4) {
        float4 o;
        o.x = acc[4 * c4 + 0] * dv;
        o.y = acc[4 * c4 + 1] * dv;
        o.z = acc[4 * c4 + 2] * dv;
        o.w = acc[4 * c4 + 3] * dv;
        orow[c4] = o;
    }
}

// layer-2 aggregation: 32-lane group per node; dis folded in xw2s; 16 gathers in flight.
__global__ __launch_bounds__(256) void k_agg2(const float* __restrict__ xw2s, const int* __restrict__ csr_src,
                                              const int* __restrict__ row_ptr, const int* __restrict__ deg,
                                              const float* __restrict__ dis, const float* __restrict__ b2,
                                              float* __restrict__ out2) {
    int lane = threadIdx.x & 31;
    int v = blockIdx.x * 8 + (threadIdx.x >> 5);
    int start = row_ptr[v];
    int cnt = deg[v];
    float acc0 = xw2s[(size_t)v * OUT_C + lane];   // self-loop term
    float acc1 = 0.f, acc2 = 0.f, acc3 = 0.f;
    for (int base = 0; base < cnt; base += 32) {
        int mcnt = min(32, cnt - base);
        int sj = 0;
        if (lane < mcnt) sj = csr_src[start + base + lane];
        int j = 0;
        for (; j + 16 <= mcnt; j += 16) {
            int s0 = __shfl(sj, j + 0, 32),  s1 = __shfl(sj, j + 1, 32);
            int s2 = __shfl(sj, j + 2, 32),  s3 = __shfl(sj, j + 3, 32);
            int s4 = __shfl(sj, j + 4, 32),  s5 = __shfl(sj, j + 5, 32);
            int s6 = __shfl(sj, j + 6, 32),  s7 = __shfl(sj, j + 7, 32);
            int s8 = __shfl(sj, j + 8, 32),  s9 = __shfl(sj, j + 9, 32);
            int sA = __shfl(sj, j + 10, 32), sB = __shfl(sj, j + 11, 32);
            int sC = __shfl(sj, j + 12, 32), sD = __shfl(sj, j + 13, 32);
            int sE = __shfl(sj, j + 14, 32), sF = __shfl(sj, j + 15, 32);
            float v0 = xw2s[(size_t)s0 * OUT_C + lane], v1 = xw2s[(size_t)s1 * OUT_C + lane];
            float v2 = xw2s[(size_t)s2 * OUT_C + lane], v3 = xw2s[(size_t)s3 * OUT_C + lane];
            float v4 = xw2s[(size_t)s4 * OUT_C + lane], v5 = xw2s[(size_t)s5 * OUT_C + lane];
            float v6 = xw2s[(size_t)s6 * OUT_C + lane], v7 = xw2s[(size_t)s7 * OUT_C + lane];
            float v8 = xw2s[(size_t)s8 * OUT_C + lane], v9 = xw2s[(size_t)s9 * OUT_C + lane];
            float vA = xw2s[(size_t)sA * OUT_C + lane], vB = xw2s[(size_t)sB * OUT_C + lane];
            float vC = xw2s[(size_t)sC * OUT_C + lane], vD = xw2s[(size_t)sD * OUT_C + lane];
            float vE = xw2s[(size_t)sE * OUT_C + lane], vF = xw2s[(size_t)sF * OUT_C + lane];
            acc0 += v0 + v4; acc1 += v1 + v5; acc2 += v2 + v6; acc3 += v3 + v7;
            acc0 += v8 + vC; acc1 += v9 + vD; acc2 += vA + vE; acc3 += vB + vF;
        }
        for (; j < mcnt; ++j) {
            int s = __shfl(sj, j, 32);
            acc0 += xw2s[(size_t)s * OUT_C + lane];
        }
    }
    out2[(size_t)v * OUT_C + lane] = fmaf(dis[v], (acc0 + acc1) + (acc2 + acc3), b2[lane]);
}

// per-graph top-30 by channel 31 (desc, stable), emit [512, 30*32] f32.
__global__ __launch_bounds__(256) void k_sort(const float* __restrict__ out2, float* __restrict__ out) {
    __shared__ float keys[NPG];
    __shared__ int order[TOPK];
    int g = blockIdx.x;
    int tid = threadIdx.x;
    int base = g * NPG;
    if (tid < NPG) keys[tid] = out2[(size_t)(base + tid) * OUT_C + (OUT_C - 1)];
    __syncthreads();
    if (tid < NPG) {
        float my = keys[tid];
        int r = 0;
        for (int j = 0; j < NPG; ++j) {
            float kj = keys[j];
            r += (kj > my) || (kj == my && j < tid);
        }
        if (r < TOPK) order[r] = tid;
    }
    __syncthreads();
    for (int idx = tid; idx < TOPK * OUT_C; idx += 256) {
        int r = idx >> 5;
        int c = idx & 31;
        int n = order[r];
        out[g * (TOPK * OUT_C) + idx] = out2[(size_t)(base + n) * OUT_C + c];
    }
}

extern "C" void kernel_launch(void* const* d_in, const int* in_sizes, int n_in,
                              void* d_out, int out_size, void* d_ws, size_t ws_size,
                              hipStream_t stream) {
    const float* x  = (const float*)d_in[0];
    const int*   ei = (const int*)d_in[1];
    const int*   srcp = ei;             // edge_index[0]
    const int*   dstp = ei + N_EDGES;   // edge_index[1]
    // d_in[2] (batch) unused: graphs are contiguous 196-node blocks.
    const float* W1 = (const float*)d_in[3];
    const float* b1 = (const float*)d_in[4];
    const float* W2 = (const float*)d_in[5];
    const float* b2 = (const float*)d_in[6];
    float* out = (float*)d_out;

    char* w = (char*)d_ws;
    int*    deg      = (int*)(w + OFF_DEG);
    int*    row_ptr  = (int*)(w + OFF_ROWPTR);
    float*  dis      = (float*)(w + OFF_DIS);
    int*    bcnt     = (int*)(w + OFF_BCNT);
    int*    arena    = (int*)(w + OFF_ARENA);
    int*    csr_src  = (int*)(w + OFF_CSR);
    float*  xw1      = (float*)(w + OFF_XW1);
    float*  h        = (float*)(w + OFF_H);
    float*  xw2s     = (float*)(w + OFF_XW2);
    float*  out2     = (float*)(w + OFF_OUT2);   // aliases arena region (dead after k_build)

    hipMemsetAsync(bcnt, 0, NB * sizeof(int), stream);
    k_phase1<<<NBUCKET_BLOCKS + N_NODES / 64, 256, 0, stream>>>(srcp, dstp, bcnt, arena, x, W1, xw1);
    k_build <<<NB, 256, 0, stream>>>(arena, bcnt, row_ptr, deg, dis, csr_src);
    k_agg1  <<<N_NODES / 4, 256, 0, stream>>>(xw1, csr_src, row_ptr, deg, dis, b1, h);
    k_mm2   <<<N_NODES / 128, 256, 0, stream>>>(h, W2, dis, xw2s);
    k_agg2  <<<N_NODES / 8, 256, 0, stream>>>(xw2s, csr_src, row_ptr, deg, dis, b2, out2);
    k_sort  <<<NUM_GRAPHS, 256, 0, stream>>>(out2, out);
}

// Round 15
// 224.797 us; speedup vs baseline: 1.1246x; 1.1246x over previous
//
#include <hip/hip_runtime.h>

#define N_NODES   100352
#define N_EDGES   1605632
#define IN_C      128
#define HID_C     64
#define OUT_C     32
#define NUM_GRAPHS 512
#define NPG       196
#define TOPK      30

#define NB        196     // buckets = dst>>9 (512 nodes each; 196*512 = 100352)
#define BCAP      10240   // arena capacity per bucket (E[nb]=8192, sigma~90)
#define LCAP      10240   // LDS staging capacity in k_build (40 KB)

typedef float v16f __attribute__((ext_vector_type(16)));

// ws layout (bytes)
#define OFF_DEG     0u          // int[N]
#define OFF_ROWPTR  401408u     // int[N]
#define OFF_DIS     802816u     // float[N]
#define OFF_BCNT    1204224u    // int[NB]
#define OFF_ARENA   1206272u    // int[NB*BCAP] (packed; dead after k_build)
#define OFF_CSR     17262592u   // int[E]
#define OFF_XW1     23685120u   // float[N*64]  (dis-scaled)
#define OFF_H       49375232u   // float[N*64]
#define OFF_XW2     75065344u   // float[N*32]  (dis-scaled)

// Pass 1: bucketize edges, packed (src<<9 | dst&511), src < 2^17.
// 32 edges/thread = 8 int4 rounds (196 blocks x 8192 edges = 2048 int4/block).
// R14 bug was r<4 here: half the edges never bucketized.
__global__ __launch_bounds__(256) void k_bucket(const int* __restrict__ src, const int* __restrict__ dst,
                                                int* __restrict__ bucket_cnt, int* __restrict__ arena) {
    __shared__ int hist[NB];
    __shared__ int cur[NB];
    int tid = threadIdx.x;
    for (int i = tid; i < NB; i += 256) hist[i] = 0;
    __syncthreads();
    int base4 = blockIdx.x * 2048 + tid;           // int4 index; 8 rounds stride 256
#pragma unroll
    for (int r = 0; r < 8; ++r) {
        int4 d = ((const int4*)dst)[base4 + r * 256];
        atomicAdd(&hist[d.x >> 9], 1);
        atomicAdd(&hist[d.y >> 9], 1);
        atomicAdd(&hist[d.z >> 9], 1);
        atomicAdd(&hist[d.w >> 9], 1);
    }
    __syncthreads();
    for (int i = tid; i < NB; i += 256) {
        int c = hist[i];
        cur[i] = (c > 0) ? atomicAdd(&bucket_cnt[i], c) : 0;
    }
    __syncthreads();
#pragma unroll
    for (int r = 0; r < 8; ++r) {
        int4 s = ((const int4*)src)[base4 + r * 256];
        int4 d = ((const int4*)dst)[base4 + r * 256];
        int p0 = atomicAdd(&cur[d.x >> 9], 1);
        int p1 = atomicAdd(&cur[d.y >> 9], 1);
        int p2 = atomicAdd(&cur[d.z >> 9], 1);
        int p3 = atomicAdd(&cur[d.w >> 9], 1);
        if (p0 < BCAP) arena[(size_t)(d.x >> 9) * BCAP + p0] = (s.x << 9) | (d.x & 511);
        if (p1 < BCAP) arena[(size_t)(d.y >> 9) * BCAP + p1] = (s.y << 9) | (d.y & 511);
        if (p2 < BCAP) arena[(size_t)(d.z >> 9) * BCAP + p2] = (s.z << 9) | (d.z & 511);
        if (p3 < BCAP) arena[(size_t)(d.w >> 9) * BCAP + p3] = (s.w << 9) | (d.w & 511);
    }
}

// Pass 2: per bucket (512 nodes). Preamble scans all 196 bucket counts in-block;
// then deg/row_ptr/dis via LDS, CSR via LDS staging.
__global__ __launch_bounds__(256) void k_build(const int* __restrict__ arena, const int* __restrict__ bucket_cnt,
                                               int* __restrict__ row_ptr,
                                               int* __restrict__ deg, float* __restrict__ dis,
                                               int* __restrict__ csr_src) {
    __shared__ int bsc[256];
    __shared__ int dloc[512];
    __shared__ int sc[512];
    __shared__ int cur[512];
    __shared__ int stage[LCAP];
    int b = blockIdx.x;
    int tid = threadIdx.x;
    int bv = (tid < NB) ? bucket_cnt[tid] : 0;
    bsc[tid] = bv;
    __syncthreads();
    for (int o = 1; o < 256; o <<= 1) {
        int a = (tid >= o) ? bsc[tid - o] : 0;
        __syncthreads();
        bsc[tid] += a;
        __syncthreads();
    }
    int nb = min(bucket_cnt[b], BCAP);
    int gbase = bsc[b] - bucket_cnt[b];            // exclusive prefix for bucket b
    const int* ap = arena + (size_t)b * BCAP;
    for (int i = tid; i < 512; i += 256) dloc[i] = 0;
    __syncthreads();
    for (int i = tid; i < nb; i += 256) {
        int e = ap[i];
        atomicAdd(&dloc[e & 511], 1);
    }
    __syncthreads();
    for (int i = tid; i < 512; i += 256) sc[i] = dloc[i];
    __syncthreads();
    for (int o = 1; o < 512; o <<= 1) {        // Hillis-Steele inclusive scan, 512 elems
        int i0 = tid, i1 = tid + 256;
        int v0 = (i0 >= o) ? sc[i0 - o] : 0;
        int v1 = (i1 >= o) ? sc[i1 - o] : 0;
        __syncthreads();
        sc[i0] += v0;
        sc[i1] += v1;
        __syncthreads();
    }
    for (int i = tid; i < 512; i += 256) {
        int d = dloc[i];
        int off = sc[i] - d;                   // exclusive prefix
        int node = b * 512 + i;
        row_ptr[node] = gbase + off;
        deg[node] = d;
        dis[node] = (float)(1.0 / sqrt((double)(d + 1)));   // +1 self-loop
        cur[i] = off;
    }
    __syncthreads();
    bool inlds = (nb <= LCAP);
    for (int i = tid; i < nb; i += 256) {
        int e = ap[i];
        int p = atomicAdd(&cur[e & 511], 1);
        int sv = ((unsigned)e) >> 9;
        if (inlds) stage[p] = sv;
        else       csr_src[gbase + p] = sv;
    }
    __syncthreads();
    if (inlds)
        for (int i = tid; i < nb; i += 256) csr_src[gbase + i] = stage[i];
}

// xw1s = dis[n] * (x @ W1). One node per thread, COL-SPLIT 4-way:
// block = 64 nodes x 4 col-quarters; ch wave-uniform -> readfirstlane -> SGPR.
__global__ __launch_bounds__(256) void k_mm1(const float* __restrict__ x, const float* __restrict__ W1,
                                             const float* __restrict__ dis, float* __restrict__ xw1s) {
    int tid = threadIdx.x;
    int n = blockIdx.x * 64 + (tid & 63);
    int ch = __builtin_amdgcn_readfirstlane((tid >> 6) * 16);   // col quarter -> SGPR
    const float4* xrow = (const float4*)(x + (size_t)n * IN_C);
    float acc[16];
#pragma unroll
    for (int c = 0; c < 16; ++c) acc[c] = 0.f;
    float4 xq = xrow[0];
#pragma unroll 1
    for (int q = 0; q < IN_C / 4; ++q) {
        float4 xn = xrow[(q + 1) & (IN_C / 4 - 1)];   // prefetch next chunk
        const float* wp = W1 + q * 4 * HID_C + ch;    // scalar address chain
        v16f w0, w1, w2, w3;
        asm volatile("s_load_dwordx16 %0, %1, 0x0"   : "=s"(w0) : "s"(wp));
        asm volatile("s_load_dwordx16 %0, %1, 0x100" : "=s"(w1) : "s"(wp));
        asm volatile("s_load_dwordx16 %0, %1, 0x200" : "=s"(w2) : "s"(wp));
        asm volatile("s_load_dwordx16 %0, %1, 0x300" : "=s"(w3) : "s"(wp));
        asm volatile("s_waitcnt lgkmcnt(0)" : "+s"(w0), "+s"(w1), "+s"(w2), "+s"(w3));
#pragma unroll
        for (int c = 0; c < 16; ++c) {
            acc[c] = fmaf(xq.x, w0[c], acc[c]);
            acc[c] = fmaf(xq.y, w1[c], acc[c]);
            acc[c] = fmaf(xq.z, w2[c], acc[c]);
            acc[c] = fmaf(xq.w, w3[c], acc[c]);
        }
        xq = xn;
    }
    float dv = dis[n];
    float4* orow = (float4*)(xw1s + (size_t)n * HID_C + ch);
#pragma unroll
    for (int c4 = 0; c4 < 4; ++c4) {
        float4 o;
        o.x = acc[4 * c4 + 0] * dv;
        o.y = acc[4 * c4 + 1] * dv;
        o.z = acc[4 * c4 + 2] * dv;
        o.w = acc[4 * c4 + 3] * dv;
        orow[c4] = o;
    }
}

// layer-1 aggregation (lean R12 form): one 64-lane wave per node; dis folded;
// 8 gather loads in flight. At the random-gather pattern floor (192 MB FETCH).
__global__ __launch_bounds__(256) void k_agg1(const float* __restrict__ xw1s, const int* __restrict__ csr_src,
                                              const int* __restrict__ row_ptr, const int* __restrict__ deg,
                                              const float* __restrict__ dis, const float* __restrict__ b1,
                                              float* __restrict__ h) {
    int lane = threadIdx.x & 63;
    int v = blockIdx.x * 4 + (threadIdx.x >> 6);
    int start = row_ptr[v];
    int cnt = deg[v];
    float acc0 = xw1s[(size_t)v * HID_C + lane];   // self-loop term (already dis-scaled)
    float acc1 = 0.f, acc2 = 0.f, acc3 = 0.f;
    for (int base = 0; base < cnt; base += 64) {
        int mcnt = min(64, cnt - base);
        int sj = 0;
        if (lane < mcnt) sj = csr_src[start + base + lane];
        int j = 0;
        for (; j + 8 <= mcnt; j += 8) {
            int s0 = __shfl(sj, j + 0), s1 = __shfl(sj, j + 1);
            int s2 = __shfl(sj, j + 2), s3 = __shfl(sj, j + 3);
            int s4 = __shfl(sj, j + 4), s5 = __shfl(sj, j + 5);
            int s6 = __shfl(sj, j + 6), s7 = __shfl(sj, j + 7);
            float v0 = xw1s[(size_t)s0 * HID_C + lane];
            float v1 = xw1s[(size_t)s1 * HID_C + lane];
            float v2 = xw1s[(size_t)s2 * HID_C + lane];
            float v3 = xw1s[(size_t)s3 * HID_C + lane];
            float v4 = xw1s[(size_t)s4 * HID_C + lane];
            float v5 = xw1s[(size_t)s5 * HID_C + lane];
            float v6 = xw1s[(size_t)s6 * HID_C + lane];
            float v7 = xw1s[(size_t)s7 * HID_C + lane];
            acc0 += v0 + v4;
            acc1 += v1 + v5;
            acc2 += v2 + v6;
            acc3 += v3 + v7;
        }
        for (; j < mcnt; ++j) {
            int s = __shfl(sj, j);
            acc0 += xw1s[(size_t)s * HID_C + lane];
        }
    }
    float o = fmaf(dis[v], (acc0 + acc1) + (acc2 + acc3), b1[lane]);
    h[(size_t)v * HID_C + lane] = fmaxf(o, 0.f);   // ReLU fused
}

// xw2s = dis[n] * (h @ W2). One node per thread, col-split 2-way (16 cols each).
__global__ __launch_bounds__(256) void k_mm2(const float* __restrict__ h, const float* __restrict__ W2,
                                             const float* __restrict__ dis, float* __restrict__ xw2s) {
    int tid = threadIdx.x;
    int n = blockIdx.x * 128 + (tid & 127);
    int ch = __builtin_amdgcn_readfirstlane((tid >> 7) * 16);   // wave-uniform col half -> SGPR
    const float4* hrow = (const float4*)(h + (size_t)n * HID_C);
    float acc[16];
#pragma unroll
    for (int c = 0; c < 16; ++c) acc[c] = 0.f;
    float4 xq = hrow[0];
#pragma unroll 1
    for (int q = 0; q < HID_C / 4; ++q) {
        float4 xn = hrow[(q + 1) & (HID_C / 4 - 1)];
        const float* wp = W2 + q * 4 * OUT_C + ch;
        v16f w0, w1, w2, w3;
        asm volatile("s_load_dwordx16 %0, %1, 0x0"   : "=s"(w0) : "s"(wp));
        asm volatile("s_load_dwordx16 %0, %1, 0x80"  : "=s"(w1) : "s"(wp));
        asm volatile("s_load_dwordx16 %0, %1, 0x100" : "=s"(w2) : "s"(wp));
        asm volatile("s_load_dwordx16 %0, %1, 0x180" : "=s"(w3) : "s"(wp));
        asm volatile("s_waitcnt lgkmcnt(0)" : "+s"(w0), "+s"(w1), "+s"(w2), "+s"(w3));
#pragma unroll
        for (int c = 0; c < 16; ++c) {
            acc[c] = fmaf(xq.x, w0[c], acc[c]);
            acc[c] = fmaf(xq.y, w1[c], acc[c]);
            acc[c] = fmaf(xq.z, w2[c], acc[c]);
            acc[c] = fmaf(xq.w, w3[c], acc[c]);
        }
        xq = xn;
    }
    float dv = dis[n];
    float4* orow = (float4*)(xw2s + (size_t)n * OUT_C + ch);
#pragma unroll
    for (int c4 = 0; c4 < 4; ++c4) {
        float4 o;
        o.x = acc[4 * c4 + 0] * dv;
        o.y = acc[4 * c4 + 1] * dv;
        o.z = acc[4 * c4 + 2] * dv;
        o.w = acc[4 * c4 + 3] * dv;
        orow[c4] = o;
    }
}

// FUSED layer-2 aggregation + sort-pool: one block per graph (196 contiguous
// nodes). Aggregate into 25 KB LDS tile, rank channel-31 keys, emit top-30.
__global__ __launch_bounds__(512) void k_agg2sort(const float* __restrict__ xw2s, const int* __restrict__ csr_src,
                                                  const int* __restrict__ row_ptr, const int* __restrict__ deg,
                                                  const float* __restrict__ dis, const float* __restrict__ b2,
                                                  float* __restrict__ out) {
    __shared__ float o2[NPG][OUT_C];   // 25088 B
    __shared__ float keys[NPG];
    __shared__ int order[TOPK];
    int g = blockIdx.x;
    int tid = threadIdx.x;
    int lane = tid & 31;
    int grp = tid >> 5;                // 16 groups of 32 lanes
    for (int i = grp; i < NPG; i += 16) {
        int v = g * NPG + i;
        int start = row_ptr[v];
        int cnt = deg[v];
        float acc0 = xw2s[(size_t)v * OUT_C + lane];   // self-loop term
        float acc1 = 0.f, acc2 = 0.f, acc3 = 0.f;
        for (int base = 0; base < cnt; base += 32) {
            int mcnt = min(32, cnt - base);
            int sj = 0;
            if (lane < mcnt) sj = csr_src[start + base + lane];
            int j = 0;
            for (; j + 8 <= mcnt; j += 8) {
                int s0 = __shfl(sj, j + 0, 32), s1 = __shfl(sj, j + 1, 32);
                int s2 = __shfl(sj, j + 2, 32), s3 = __shfl(sj, j + 3, 32);
                int s4 = __shfl(sj, j + 4, 32), s5 = __shfl(sj, j + 5, 32);
                int s6 = __shfl(sj, j + 6, 32), s7 = __shfl(sj, j + 7, 32);
                float v0 = xw2s[(size_t)s0 * OUT_C + lane];
                float v1 = xw2s[(size_t)s1 * OUT_C + lane];
                float v2 = xw2s[(size_t)s2 * OUT_C + lane];
                float v3 = xw2s[(size_t)s3 * OUT_C + lane];
                float v4 = xw2s[(size_t)s4 * OUT_C + lane];
                float v5 = xw2s[(size_t)s5 * OUT_C + lane];
                float v6 = xw2s[(size_t)s6 * OUT_C + lane];
                float v7 = xw2s[(size_t)s7 * OUT_C + lane];
                acc0 += v0 + v4;
                acc1 += v1 + v5;
                acc2 += v2 + v6;
                acc3 += v3 + v7;
            }
            for (; j < mcnt; ++j) {
                int s = __shfl(sj, j, 32);
                acc0 += xw2s[(size_t)s * OUT_C + lane];
            }
        }
        float val = fmaf(dis[v], (acc0 + acc1) + (acc2 + acc3), b2[lane]);
        o2[i][lane] = val;
        if (lane == OUT_C - 1) keys[i] = val;
    }
    __syncthreads();
    // rank (desc, stable) over 196 keys
    for (int i = tid; i < NPG; i += 512) {
        float my = keys[i];
        int r = 0;
        for (int j = 0; j < NPG; ++j) {
            float kj = keys[j];
            r += (kj > my) || (kj == my && j < i);
        }
        if (r < TOPK) order[r] = i;
    }
    __syncthreads();
    for (int idx = tid; idx < TOPK * OUT_C; idx += 512) {
        int r = idx >> 5;
        int c = idx & 31;
        out[g * (TOPK * OUT_C) + idx] = o2[order[r]][c];
    }
}

extern "C" void kernel_launch(void* const* d_in, const int* in_sizes, int n_in,
                              void* d_out, int out_size, void* d_ws, size_t ws_size,
                              hipStream_t stream) {
    const float* x  = (const float*)d_in[0];
    const int*   ei = (const int*)d_in[1];
    const int*   srcp = ei;             // edge_index[0]
    const int*   dstp = ei + N_EDGES;   // edge_index[1]
    // d_in[2] (batch) unused: graphs are contiguous 196-node blocks.
    const float* W1 = (const float*)d_in[3];
    const float* b1 = (const float*)d_in[4];
    const float* W2 = (const float*)d_in[5];
    const float* b2 = (const float*)d_in[6];
    float* out = (float*)d_out;

    char* w = (char*)d_ws;
    int*    deg      = (int*)(w + OFF_DEG);
    int*    row_ptr  = (int*)(w + OFF_ROWPTR);
    float*  dis      = (float*)(w + OFF_DIS);
    int*    bcnt     = (int*)(w + OFF_BCNT);
    int*    arena    = (int*)(w + OFF_ARENA);
    int*    csr_src  = (int*)(w + OFF_CSR);
    float*  xw1s     = (float*)(w + OFF_XW1);
    float*  h        = (float*)(w + OFF_H);
    float*  xw2s     = (float*)(w + OFF_XW2);

    hipMemsetAsync(bcnt, 0, NB * sizeof(int), stream);
    k_bucket<<<N_EDGES / (256 * 32), 256, 0, stream>>>(srcp, dstp, bcnt, arena);
    k_build <<<NB, 256, 0, stream>>>(arena, bcnt, row_ptr, deg, dis, csr_src);
    k_mm1   <<<N_NODES / 64, 256, 0, stream>>>(x, W1, dis, xw1s);
    k_agg1  <<<N_NODES / 4, 256, 0, stream>>>(xw1s, csr_src, row_ptr, deg, dis, b1, h);
    k_mm2   <<<N_NODES / 128, 256, 0, stream>>>(h, W2, dis, xw2s);
    k_agg2sort<<<NUM_GRAPHS, 512, 0, stream>>>(xw2s, csr_src, row_ptr, deg, dis, b2, out);
}